// Round 1
// baseline (554.208 us; speedup 1.0000x reference)
//
#include <hip/hip_runtime.h>

#define NEG_INF (-1e9f)
#define SCALE_F 0.08838834764831845f

typedef __attribute__((ext_vector_type(8))) short short8;
typedef __attribute__((ext_vector_type(4))) float float4v;

__device__ __constant__ int cDR[8] = {1,1,0,-1,-1,-1,0,1};
__device__ __constant__ int cDC[8] = {0,1,1,1,0,-1,-1,-1};
__device__ __constant__ int cKR[8] = {2,1,-1,-2,-2,-1,1,2};
__device__ __constant__ int cKC[8] = {1,2,2,1,-1,-2,-2,-1};

__device__ inline ushort f2bf(float f) {
  union { float f; unsigned u; } a; a.f = f;
  unsigned u = a.u;
  return (ushort)((u + 0x7FFFu + ((u >> 16) & 1u)) >> 16);
}

__device__ inline short8 lds_load8(const ushort* p) {
  union { short8 v; ushort4 h[2]; } u;
  u.h[0] = *(const ushort4*)(p);
  u.h[1] = *(const ushort4*)(p + 4);
  return u.v;
}

// Kernel 0: convert Wq (1024x128) | Wk (1024x128) f32 -> bf16, transposed to
// Wt[n][k], n in 0..255 (0..127 = q cols, 128..255 = k cols), k in 0..1023.
__global__ void wconv_kernel(const float* __restrict__ Wq,
                             const float* __restrict__ Wk,
                             ushort* __restrict__ Wt) {
  int n = blockIdx.x;                       // 0..255
  const float* W = (n < 128) ? Wq : Wk;
  int c = n & 127;
  for (int k = threadIdx.x; k < 1024; k += 256)
    Wt[n * 1024 + k] = f2bf(W[k * 128 + c]);
}

// Kernel 2: promotion logits. Only rows f=48..55, 9 cols each. Writes directly
// into out[b, f*73 + 64 + n]. Main kernel skips these positions.
__global__ void up_kernel(const float* __restrict__ x,
                          const float* __restrict__ Wu,
                          const float* __restrict__ bu,
                          float* __restrict__ out) {
  int b = blockIdx.x;
  int t = threadIdx.x;
  if (t >= 72) return;
  int row = t / 9;
  int n = t - row * 9;
  int f = 48 + row;
  const float* xr = x + ((size_t)b * 64 + f) * 1024;
  float acc = 0.f;
  for (int k = 0; k < 1024; k += 4) {
    float4 xv = *(const float4*)(xr + k);
    acc += xv.x * Wu[(k + 0) * 9 + n];
    acc += xv.y * Wu[(k + 1) * 9 + n];
    acc += xv.z * Wu[(k + 2) * 9 + n];
    acc += xv.w * Wu[(k + 3) * 9 + n];
  }
  out[(size_t)b * 4672 + f * 73 + 64 + n] = acc + bu[n];
}

// Main kernel: one block per batch element.
// Phase 1: GEMM1 [x(64x1024) @ Wt^T(1024x256)] -> q|k accumulators (bf16 MFMA)
// Phase 2: epilogue -> qs/ks in LDS (bias, scale folded into q)
// Phase 3: GEMM2 S = q' @ k'^T (64x64)
// Phase 4: gather planes + masks, write 64x73 output row.
__global__ __launch_bounds__(256, 3)
void apol_main(const float* __restrict__ x,
               const float* __restrict__ bq,
               const float* __restrict__ bk,
               const ushort* __restrict__ Wt,
               float* __restrict__ out) {
  // LDS union:
  //  phase1: xs[64][68] bf16 (8704 B) + wt[256][68] bf16 (34816 B) = 43520 B
  //  phase2: qs[64][132] (16896 B) + ks[64][132] (16896 B)        = 33792 B
  //  phase3: Sl[64][65] f32                                       = 16640 B
  __shared__ __align__(16) char smem[43520];
  ushort* xs = (ushort*)smem;            // stride 68
  ushort* wt = (ushort*)(smem + 8704);   // stride 68
  ushort* qs = (ushort*)smem;            // stride 132
  ushort* ks = (ushort*)(smem + 16896);  // stride 132
  float*  Sl = (float*)smem;             // stride 65

  const int b    = blockIdx.x;
  const int tid  = threadIdx.x;
  const int w    = tid >> 6;    // wave 0..3
  const int lane = tid & 63;
  const int l15  = lane & 15;
  const int qd   = lane >> 4;   // quad 0..3

  const float* xb = x + (size_t)b * (64 * 1024);

  float4v acc[4][4];
  #pragma unroll
  for (int i = 0; i < 4; ++i)
    #pragma unroll
    for (int j = 0; j < 4; ++j)
      acc[i][j] = (float4v){0.f, 0.f, 0.f, 0.f};

  // ---------------- GEMM1: K loop over 16 chunks of BK=64 ----------------
  #pragma unroll 1
  for (int kc = 0; kc < 16; ++kc) {
    const int k0 = kc * 64;
    // stage x chunk: 64 rows x 64 f32 -> bf16. 1024 float4 slots.
    #pragma unroll
    for (int i = 0; i < 4; ++i) {
      int s = tid + i * 256;
      int f = s >> 4, seg = s & 15;
      float4 v = *(const float4*)(xb + f * 1024 + k0 + seg * 4);
      ushort4 h;
      h.x = f2bf(v.x); h.y = f2bf(v.y); h.z = f2bf(v.z); h.w = f2bf(v.w);
      *(ushort4*)(&xs[f * 68 + seg * 4]) = h;
    }
    // stage Wt chunk: 256 rows x 64 bf16. 2048 16B slots.
    #pragma unroll
    for (int i = 0; i < 8; ++i) {
      int s = tid + i * 256;
      int n = s >> 3, seg = s & 7;
      uint4 v = *(const uint4*)(Wt + n * 1024 + k0 + seg * 8);
      ushort* dst = &wt[n * 68 + seg * 8];
      *(uint2*)(dst)     = make_uint2(v.x, v.y);
      *(uint2*)(dst + 4) = make_uint2(v.z, v.w);
    }
    __syncthreads();
    // compute: 2 k-steps of 32
    #pragma unroll
    for (int kk = 0; kk < 2; ++kk) {
      const int kb = kk * 32 + qd * 8;
      short8 af[4], bf[4];
      #pragma unroll
      for (int mt = 0; mt < 4; ++mt)
        af[mt] = lds_load8(&xs[(mt * 16 + l15) * 68 + kb]);
      #pragma unroll
      for (int nt = 0; nt < 4; ++nt)
        bf[nt] = lds_load8(&wt[(w * 64 + nt * 16 + l15) * 68 + kb]);
      #pragma unroll
      for (int mt = 0; mt < 4; ++mt)
        #pragma unroll
        for (int nt = 0; nt < 4; ++nt)
          acc[mt][nt] = __builtin_amdgcn_mfma_f32_16x16x32_bf16(
              af[mt], bf[nt], acc[mt][nt], 0, 0, 0);
    }
    __syncthreads();
  }

  // ---------------- epilogue: acc -> qs/ks (bf16, bias, scale) -----------
  #pragma unroll
  for (int nt = 0; nt < 4; ++nt) {
    int C = w * 64 + nt * 16 + l15;      // output column 0..255
    bool isq = (C < 128);
    int p = isq ? C : (C - 128);
    float bias = isq ? bq[p] : bk[p];
    ushort* dstb = isq ? qs : ks;
    #pragma unroll
    for (int mt = 0; mt < 4; ++mt) {
      #pragma unroll
      for (int r = 0; r < 4; ++r) {
        int row = mt * 16 + qd * 4 + r;
        float v = acc[mt][nt][r] + bias;
        if (isq) v *= SCALE_F;
        dstb[row * 132 + p] = f2bf(v);
      }
    }
  }
  __syncthreads();

  // ---------------- GEMM2: S = q' @ k'^T (64x64), K=128 ------------------
  float4v acc2[4];
  #pragma unroll
  for (int nt = 0; nt < 4; ++nt) acc2[nt] = (float4v){0.f, 0.f, 0.f, 0.f};
  #pragma unroll
  for (int kp = 0; kp < 4; ++kp) {
    int kb = kp * 32 + qd * 8;
    short8 a2 = lds_load8(&qs[(w * 16 + l15) * 132 + kb]);
    #pragma unroll
    for (int nt = 0; nt < 4; ++nt) {
      short8 b2 = lds_load8(&ks[(nt * 16 + l15) * 132 + kb]);
      acc2[nt] = __builtin_amdgcn_mfma_f32_16x16x32_bf16(a2, b2, acc2[nt], 0, 0, 0);
    }
  }
  __syncthreads();  // done reading qs/ks; Sl overwrites that region
  #pragma unroll
  for (int nt = 0; nt < 4; ++nt)
    #pragma unroll
    for (int r = 0; r < 4; ++r)
      Sl[(w * 16 + qd * 4 + r) * 65 + nt * 16 + l15] = acc2[nt][r];
  __syncthreads();

  // ---------------- gather + masks + store -------------------------------
  float* outb = out + (size_t)b * 4672;
  for (int idx = tid; idx < 4672; idx += 256) {
    int f = idx / 73;
    int j = idx - f * 73;
    float val;
    if (j < 64) {
      int rr = f >> 3, cc = f & 7;
      int nr, nc;
      if (j < 56) {
        int d = j / 7;
        int dist = j - d * 7 + 1;
        nr = rr + cDR[d] * dist;
        nc = cc + cDC[d] * dist;
      } else {
        nr = rr + cKR[j - 56];
        nc = cc + cKC[j - 56];
      }
      if (nr >= 0 && nr < 8 && nc >= 0 && nc < 8)
        val = Sl[f * 65 + nr * 8 + nc];
      else
        val = NEG_INF;
    } else {
      if (f >= 48 && f < 56) continue;  // up_kernel writes promo rows
      val = NEG_INF;
    }
    outb[idx] = val;
  }
}

extern "C" void kernel_launch(void* const* d_in, const int* in_sizes, int n_in,
                              void* d_out, int out_size, void* d_ws, size_t ws_size,
                              hipStream_t stream) {
  const float* x  = (const float*)d_in[0];
  const float* Wq = (const float*)d_in[1];
  const float* bq = (const float*)d_in[2];
  const float* Wk = (const float*)d_in[3];
  const float* bk = (const float*)d_in[4];
  const float* Wu = (const float*)d_in[5];
  const float* bu = (const float*)d_in[6];
  float* out = (float*)d_out;
  ushort* Wt = (ushort*)d_ws;  // 256*1024 bf16 = 512 KB

  const int B = in_sizes[0] / (64 * 1024);

  wconv_kernel<<<256, 256, 0, stream>>>(Wq, Wk, Wt);
  apol_main<<<B, 256, 0, stream>>>(x, bq, bk, Wt, out);
  up_kernel<<<B, 128, 0, stream>>>(x, Wu, bu, out);
}

// Round 2
// 403.018 us; speedup vs baseline: 1.3751x; 1.3751x over previous
//
#include <hip/hip_runtime.h>

#define NEG_INF (-1e9f)
#define SCALE_F 0.08838834764831845f

typedef __attribute__((ext_vector_type(8))) short short8;
typedef __attribute__((ext_vector_type(4))) float float4v;

__device__ __constant__ int cDR[8] = {1,1,0,-1,-1,-1,0,1};
__device__ __constant__ int cDC[8] = {0,1,1,1,0,-1,-1,-1};
__device__ __constant__ int cKR[8] = {2,1,-1,-2,-2,-1,1,2};
__device__ __constant__ int cKC[8] = {1,2,2,1,-1,-2,-2,-1};

__device__ __forceinline__ ushort f2bf(float f) {
  union { float f; unsigned u; } a; a.f = f;
  unsigned u = a.u;
  return (ushort)((u + 0x7FFFu + ((u >> 16) & 1u)) >> 16);
}

// async 16B/lane copy: global -> LDS. ldsbase must be wave-uniform; lane i
// receives bytes [i*16, i*16+16).
__device__ __forceinline__ void glds16(const void* g, void* l) {
  __builtin_amdgcn_global_load_lds(
      (const __attribute__((address_space(1))) unsigned int*)g,
      (__attribute__((address_space(3))) unsigned int*)l, 16, 0, 0);
}

// truncation-pack 8 f32 -> 8 bf16 (error 2^-8, irrelevant vs threshold)
__device__ __forceinline__ short8 pack8(float4 a, float4 b) {
  union { short8 v; unsigned u[4]; } o;
  unsigned a0 = __float_as_uint(a.x), a1 = __float_as_uint(a.y);
  unsigned a2 = __float_as_uint(a.z), a3 = __float_as_uint(a.w);
  unsigned b0 = __float_as_uint(b.x), b1 = __float_as_uint(b.y);
  unsigned b2 = __float_as_uint(b.z), b3 = __float_as_uint(b.w);
  o.u[0] = (a1 & 0xFFFF0000u) | (a0 >> 16);
  o.u[1] = (a3 & 0xFFFF0000u) | (a2 >> 16);
  o.u[2] = (b1 & 0xFFFF0000u) | (b0 >> 16);
  o.u[3] = (b3 & 0xFFFF0000u) | (b2 >> 16);
  return o.v;
}

// Wsw layout: [kc][row][sseg*8+j] bf16, chunk-major (18432 elems/chunk),
// row 0..287: 0-127 Wq cols, 128-255 Wk cols, 256-264 Wu cols, 265-287 zero.
// XOR swizzle: position sseg holds original k-seg (sseg ^ (row&7)); 16B
// granules stay contiguous so global_load_lds copies are linear.
__global__ void wconv_kernel(const float* __restrict__ Wq,
                             const float* __restrict__ Wk,
                             const float* __restrict__ Wu,
                             ushort* __restrict__ Wsw) {
  int row = blockIdx.x;  // 0..287
  for (int k = threadIdx.x; k < 1024; k += 256) {
    float v;
    if (row < 128)      v = Wq[k * 128 + row];
    else if (row < 256) v = Wk[k * 128 + (row - 128)];
    else if (row < 265) v = Wu[k * 9 + (row - 256)];
    else                v = 0.f;
    int kc = k >> 6, kin = k & 63, seg = kin >> 3, j = kin & 7;
    int sseg = seg ^ (row & 7);
    Wsw[(size_t)kc * 18432 + row * 64 + sseg * 8 + j] = f2bf(v);
  }
}

__global__ __launch_bounds__(256, 3)
void apol_main(const float* __restrict__ x,
               const float* __restrict__ bq,
               const float* __restrict__ bk,
               const float* __restrict__ bu,
               const ushort* __restrict__ Wsw,
               float* __restrict__ out) {
  // LDS union:
  //  phase1: xs f32[64][64] (16384 B) + wt bf16[288][64] (36864 B) = 53248 B
  //  phase2: qs[64][132] + ks[64][132] bf16                        = 33792 B
  //  phase3: Sl f32[64][65]                                        = 16640 B
  __shared__ __align__(16) char smem[53248];
  char*   xsB = smem;            // f32 x tile, XOR-swizzled granules
  char*   wtB = smem + 16384;    // bf16 W tile (copied pre-swizzled)
  ushort* qs  = (ushort*)smem;
  ushort* ks  = (ushort*)(smem + 16896);
  float*  Sl  = (float*)smem;

  const int tid = threadIdx.x;
  const int w = tid >> 6, lane = tid & 63;
  const int l15 = lane & 15, qd = lane >> 4;
  const char* xb = (const char*)(x + (size_t)blockIdx.x * 65536);
  const char* WsB = (const char*)Wsw;

  // x staging source offsets: 4 calls/wave, 1KB each (4 rows x 256B).
  int xsrc[4], xlds[4];
  #pragma unroll
  for (int c = 0; c < 4; ++c) {
    int g = (c * 4 + w) * 64 + lane;   // granule 0..1023
    int row = g >> 4, sg = g & 15;
    xsrc[c] = row * 4096 + ((sg ^ (row & 7)) * 16);
    xlds[c] = (c * 4 + w) * 1024;      // wave-uniform
  }

  // A-fragment LDS byte addrs: frag (mt,kk) half h: row=mt*16+l15,
  // granule g=kk*8+qd*2+h, swizzled.
  int aaddr[4][2][2];
  #pragma unroll
  for (int mt = 0; mt < 4; ++mt) {
    int row = mt * 16 + l15;
    #pragma unroll
    for (int kk = 0; kk < 2; ++kk)
      #pragma unroll
      for (int h = 0; h < 2; ++h)
        aaddr[mt][kk][h] = row * 256 + (((kk * 8 + qd * 2 + h) ^ (row & 7)) * 16);
  }
  // B-fragment LDS byte addrs: row=w*64+nt*16+l15, k-seg kk*4+qd, swizzled.
  int baddr[4][2], uaddr[2];
  #pragma unroll
  for (int nt = 0; nt < 4; ++nt) {
    int row = w * 64 + nt * 16 + l15;
    #pragma unroll
    for (int kk = 0; kk < 2; ++kk)
      baddr[nt][kk] = row * 128 + (((kk * 4 + qd) ^ (l15 & 7)) * 16);
  }
  #pragma unroll
  for (int kk = 0; kk < 2; ++kk)
    uaddr[kk] = (256 + l15) * 128 + (((kk * 4 + qd) ^ (l15 & 7)) * 16);

  float4v acc[4][4];
  #pragma unroll
  for (int i = 0; i < 4; ++i)
    #pragma unroll
    for (int j = 0; j < 4; ++j)
      acc[i][j] = (float4v){0.f, 0.f, 0.f, 0.f};
  float4v aup = (float4v){0.f, 0.f, 0.f, 0.f};

  // ---------------- GEMM1: 16 chunks of BK=64 ----------------
  #pragma unroll 1
  for (int kc = 0; kc < 16; ++kc) {
    // issue async staging: x 16KB (4 calls) + W 36KB (9 calls)
    #pragma unroll
    for (int c = 0; c < 4; ++c)
      glds16(xb + kc * 256 + xsrc[c], xsB + xlds[c]);
    const char* wsrc = WsB + (size_t)kc * 36864 + (size_t)lane * 16;
    #pragma unroll
    for (int c = 0; c < 9; ++c)
      glds16(wsrc + (c * 4 + w) * 1024, wtB + (c * 4 + w) * 1024);
    __syncthreads();

    #pragma unroll
    for (int kk = 0; kk < 2; ++kk) {
      short8 af[4];
      #pragma unroll
      for (int mt = 0; mt < 4; ++mt) {
        float4 g0 = *(const float4*)(xsB + aaddr[mt][kk][0]);
        float4 g1 = *(const float4*)(xsB + aaddr[mt][kk][1]);
        af[mt] = pack8(g0, g1);
      }
      short8 bf[4];
      #pragma unroll
      for (int nt = 0; nt < 4; ++nt)
        bf[nt] = *(const short8*)(wtB + baddr[nt][kk]);
      #pragma unroll
      for (int mt = 0; mt < 4; ++mt)
        #pragma unroll
        for (int nt = 0; nt < 4; ++nt)
          acc[mt][nt] = __builtin_amdgcn_mfma_f32_16x16x32_bf16(
              af[mt], bf[nt], acc[mt][nt], 0, 0, 0);
      if (w == 3) {  // promo columns: Wu as B-rows 256..271
        short8 ub = *(const short8*)(wtB + uaddr[kk]);
        aup = __builtin_amdgcn_mfma_f32_16x16x32_bf16(af[3], ub, aup, 0, 0, 0);
      }
    }
    __syncthreads();
  }

  float* outb = out + (size_t)blockIdx.x * 4672;

  // promo writes: wave 3, C rows 0..7 <-> x rows 48..55, cols 0..8
  if (w == 3 && qd < 2 && l15 < 9) {
    float bias = bu[l15];
    #pragma unroll
    for (int r = 0; r < 4; ++r) {
      int f = 48 + qd * 4 + r;
      outb[f * 73 + 64 + l15] = aup[r] + bias;
    }
  }

  // ---------------- epilogue: acc -> qs/ks (bias, scale) ----------------
  #pragma unroll
  for (int nt = 0; nt < 4; ++nt) {
    int C = w * 64 + nt * 16 + l15;
    bool isq = (C < 128);
    int p = isq ? C : (C - 128);
    float bias = isq ? bq[p] : bk[p];
    ushort* dstb = isq ? qs : ks;
    #pragma unroll
    for (int mt = 0; mt < 4; ++mt)
      #pragma unroll
      for (int r = 0; r < 4; ++r) {
        int row = mt * 16 + qd * 4 + r;
        float v = acc[mt][nt][r] + bias;
        if (isq) v *= SCALE_F;
        dstb[row * 132 + p] = f2bf(v);
      }
  }
  __syncthreads();

  // ---------------- GEMM2: S = q' @ k'^T (64x64), K=128 ----------------
  float4v acc2[4];
  #pragma unroll
  for (int nt = 0; nt < 4; ++nt) acc2[nt] = (float4v){0.f, 0.f, 0.f, 0.f};
  #pragma unroll
  for (int kp = 0; kp < 4; ++kp) {
    int kb = kp * 32 + qd * 8;
    short8 a2 = *(const short8*)((const char*)&qs[(w * 16 + l15) * 132 + kb]);
    #pragma unroll
    for (int nt = 0; nt < 4; ++nt) {
      short8 b2 = *(const short8*)((const char*)&ks[(nt * 16 + l15) * 132 + kb]);
      acc2[nt] = __builtin_amdgcn_mfma_f32_16x16x32_bf16(a2, b2, acc2[nt], 0, 0, 0);
    }
  }
  __syncthreads();
  #pragma unroll
  for (int nt = 0; nt < 4; ++nt)
    #pragma unroll
    for (int r = 0; r < 4; ++r)
      Sl[(w * 16 + qd * 4 + r) * 65 + nt * 16 + l15] = acc2[nt][r];
  __syncthreads();

  // ---------------- gather + masks + store ----------------
  for (int idx = tid; idx < 4672; idx += 256) {
    int f = idx / 73;
    int j = idx - f * 73;
    float val;
    if (j < 64) {
      int rr = f >> 3, cc = f & 7;
      int nr, nc;
      if (j < 56) {
        int d = j / 7;
        int dist = j - d * 7 + 1;
        nr = rr + cDR[d] * dist;
        nc = cc + cDC[d] * dist;
      } else {
        nr = rr + cKR[j - 56];
        nc = cc + cKC[j - 56];
      }
      val = (nr >= 0 && nr < 8 && nc >= 0 && nc < 8) ? Sl[f * 65 + nr * 8 + nc]
                                                     : NEG_INF;
    } else {
      if (f >= 48 && f < 56) continue;  // promo rows written from aup
      val = NEG_INF;
    }
    outb[idx] = val;
  }
}

extern "C" void kernel_launch(void* const* d_in, const int* in_sizes, int n_in,
                              void* d_out, int out_size, void* d_ws, size_t ws_size,
                              hipStream_t stream) {
  const float* x  = (const float*)d_in[0];
  const float* Wq = (const float*)d_in[1];
  const float* bq = (const float*)d_in[2];
  const float* Wk = (const float*)d_in[3];
  const float* bk = (const float*)d_in[4];
  const float* Wu = (const float*)d_in[5];
  const float* bu = (const float*)d_in[6];
  float* out = (float*)d_out;
  ushort* Wsw = (ushort*)d_ws;  // 16*18432 bf16 = 576 KB

  const int B = in_sizes[0] / 65536;

  wconv_kernel<<<288, 256, 0, stream>>>(Wq, Wk, Wu, Wsw);
  apol_main<<<B, 256, 0, stream>>>(x, bq, bk, bu, Wsw, out);
}